// Round 9
// baseline (13241.211 us; speedup 1.0000x reference)
//
#include <hip/hip_runtime.h>
#include <stdint.h>

typedef unsigned int u32;
typedef unsigned short u16;
typedef unsigned long long u64;
typedef _Float16 f16;
typedef _Float16 h2_t __attribute__((ext_vector_type(2)));
typedef _Float16 f16x4 __attribute__((ext_vector_type(4)));
typedef _Float16 f16x8 __attribute__((ext_vector_type(8)));
typedef float f32x4 __attribute__((ext_vector_type(4)));
typedef float f32x16 __attribute__((ext_vector_type(16)));
typedef u32 u32x4 __attribute__((ext_vector_type(4)));

#define TT 512
#define NF 128
#define NTOT (256 * TT)

// ---- ws layout (bytes) ----
#define OFF_WA0   0u          // 786432 f16 = 1,572,864
#define OFF_WA1   1572864u    // 524288 f16 = 1,048,576
#define OFF_WAH   2621440u    // 131072 f16 =   262,144
#define OFF_GSUM  2883584u    // 128 f32 (+pad)
#define OFF_GSQ   2884096u    // 128 f32 (+pad)
#define OFF_CTR   2884608u    // 512 u32 (16 counters, 128B apart)
#define OFF_GH1   2886656u    // 8 groups * 2048 u64 = 131,072
#define OFF_GH2   3017728u    // 131,072
#define OFF_Y     3148800u    // 131072*128 f16 = 33,554,432

__device__ __forceinline__ float sigf(float x) { return 1.0f / (1.0f + __expf(-x)); }
__device__ __forceinline__ float tanh_fast(float x) { return 1.0f - 2.0f / (__expf(2.0f * x) + 1.0f); }

// ---------------- prep: pack weights into per-wave MFMA A-fragments (same as r8) --------
__global__ void prep_kernel(const float* __restrict__ Wih0, const float* __restrict__ Whh0,
                            const float* __restrict__ Wih1, const float* __restrict__ Whh1,
                            const float* __restrict__ W1,
                            f16* __restrict__ WA0, f16* __restrict__ WA1, f16* __restrict__ WAH,
                            float* __restrict__ gz, u32* __restrict__ ctr) {
    int idx = blockIdx.x * 256 + threadIdx.x;
    const int n0 = 786432, n1 = 524288, n2 = 131072;
    if (idx < n0) {
        int u = idx >> 9, r9 = idx & 511;
        int lane = r9 >> 3, j = r9 & 7;
        int ks = u % 6; u /= 6;
        int wv = u & 7, w = u >> 3;
        int lr = lane & 31, h = lane >> 5;
        int r = ((lr >> 3) << 8) + 8 * w + (lr & 7);
        int seg = ks >> 1, sig = ks & 1;
        int c = 256 * seg + 32 * wv + 16 * sig + 8 * h + j;
        float v = (c < 512) ? Wih0[r * 512 + c] : Whh0[r * 256 + (c - 512)];
        WA0[idx] = (f16)v;
    } else if (idx < n0 + n1) {
        int i2 = idx - n0;
        int lane = (i2 >> 3) & 63, j = i2 & 7;
        int ks = (i2 >> 9) & 3, wv = (i2 >> 11) & 7, w = i2 >> 14;
        int lr = lane & 31, h = lane >> 5;
        int r = ((lr >> 3) << 8) + 8 * w + (lr & 7);
        int sig = ks & 1;
        int c = 32 * wv + 16 * sig + 8 * h + j;
        float v = (ks >> 1) ? Whh1[r * 256 + c] : Wih1[r * 256 + c];
        WA1[i2] = (f16)v;
    } else if (idx < n0 + n1 + n2) {
        int i2 = idx - n0 - n1;
        int u = i2 >> 9, r9 = i2 & 511;
        int lane = r9 >> 3, j = r9 & 7;
        int ks = u & 7, w = u >> 3;
        int m = lane & 15, hh = lane >> 4;
        int k = 32 * ks + 8 * hh + j;
        float v = (m < 4) ? W1[(4 * w + m) * 256 + k] : 0.f;
        WAH[i2] = (f16)v;
    } else if (idx < n0 + n1 + n2 + 256) {
        gz[idx - n0 - n1 - n2] = 0.f;     // gsum[128] + gsq[128]
    } else if (idx < n0 + n1 + n2 + 256 + 512) {
        ctr[idx - n0 - n1 - n2 - 256] = 0u;
    }
}

#define MFMA32L(A, BP, C) (C) = __builtin_amdgcn_mfma_f32_32x32x16_f16( \
    __builtin_bit_cast(f16x8, (A)), __builtin_bit_cast(f16x8, *(const uint4*)(BP)), (C), 0, 0, 0)
#define MFMA32R(A, B, C) (C) = __builtin_amdgcn_mfma_f32_32x32x16_f16( \
    __builtin_bit_cast(f16x8, (A)), __builtin_bit_cast(f16x8, (B)), (C), 0, 0, 0)

#define ZZWR(KW, C) do { \
    f32x4 v0_ = {(C)[0], (C)[1], (C)[2], (C)[3]};    *(f32x4*)&zz[KW][n32][4 * h32] = v0_; \
    f32x4 v1_ = {(C)[4], (C)[5], (C)[6], (C)[7]};    *(f32x4*)&zz[KW][n32][8 + 4 * h32] = v1_; \
    f32x4 v2_ = {(C)[8], (C)[9], (C)[10], (C)[11]};  *(f32x4*)&zz[KW][n32][16 + 4 * h32] = v2_; \
    f32x4 v3_ = {(C)[12], (C)[13], (C)[14], (C)[15]}; *(f32x4*)&zz[KW][n32][24 + 4 * h32] = v3_; } while (0)

// coherent (device-visible) wide exchange primitives
#define GATHER2(F0, F1, P0, P1) asm volatile( \
    "global_load_dwordx4 %0, %2, off sc0 sc1\n\t" \
    "global_load_dwordx4 %1, %3, off sc0 sc1\n\t" \
    "s_waitcnt vmcnt(0)" \
    : "=&v"(F0), "=&v"(F1) : "v"(P0), "v"(P1) : "memory")

#define PUBX4(PTR, DATA) asm volatile( \
    "global_store_dwordx4 %0, %1, off sc0 sc1" :: "v"(PTR), "v"(DATA) : "memory")

#define POLL(CTRP, TGT) do { \
    int gu_ = 0; \
    while (__hip_atomic_load((CTRP), __ATOMIC_RELAXED, __HIP_MEMORY_SCOPE_AGENT) < (TGT) \
           && ++gu_ < 300000) {} } while (0)

#define HEAD_BODY(TIDX) do { \
    f32x4 C_ = {}; \
    _Pragma("unroll") \
    for (int ks_ = 0; ks_ < 8; ++ks_) \
        C_ = __builtin_amdgcn_mfma_f32_16x16x32_f16( \
            __builtin_bit_cast(f16x8, ah[ks_]), \
            __builtin_bit_cast(f16x8, \
                *(const uint4*)&Xh2[wv * 16 + (lane & 15)][32 * ks_ + 8 * ((lane >> 4) & 3)]), \
            C_, 0, 0, 0); \
    if (lane < 16) { \
        float y0 = C_[0] + b1s[0], y1 = C_[1] + b1s[1]; \
        float y2 = C_[2] + b1s[2], y3 = C_[3] + b1s[3]; \
        ys0 += y0; yq0 += y0 * y0; ys1 += y1; yq1 += y1 * y1; \
        ys2 += y2; yq2 += y2 * y2; ys3 += y3; yq3 += y3 * y3; \
        f16x4 yp; yp[0] = (f16)y0; yp[1] = (f16)y1; yp[2] = (f16)y2; yp[3] = (f16)y3; \
        int b_ = wv * 16 + lane; \
        ((u64*)ybuf)[((size_t)(g * 32 + b_) * 512 + (TIDX)) * 32 + w] = __builtin_bit_cast(u64, yp); \
    } } while (0)

// cell phase: reduce zz + activations + shfl-collapse + direct publish + drain + count
#define CELL_PUBLISH(BCS, CSTATE, SRC, CTRP) do { \
    float z0 = BCS[cj], z1 = BCS[8 + cj], z2 = BCS[16 + cj], z3 = BCS[24 + cj]; \
    _Pragma("unroll") \
    for (int kw_ = 0; kw_ < 8; ++kw_) { \
        z0 += zz[kw_][cb][cj];      z1 += zz[kw_][cb][8 + cj]; \
        z2 += zz[kw_][cb][16 + cj]; z3 += zz[kw_][cb][24 + cj]; \
    } \
    float c_ = sigf(z1) * (CSTATE) + sigf(z0) * tanh_fast(z2); \
    (CSTATE) = c_; \
    f16 hf_ = (f16)(sigf(z3) * tanh_fast(c_)); \
    u32 hb_ = (u32)__builtin_bit_cast(u16, hf_); \
    u32 p01_ = hb_ | ((u32)__shfl_xor((int)hb_, 1, 64) << 16); \
    u32 p23_ = (u32)__shfl_xor((int)p01_, 2, 64); \
    u32 p45_ = (u32)__shfl_xor((int)p01_, 4, 64); \
    u32 p67_ = (u32)__shfl_xor((int)p23_, 4, 64); \
    if (cj == 0) { \
        u32x4 word_ = {p01_, p23_, p45_, p67_}; \
        PUBX4((void*)((SRC) + ((cb << 5) + w) * 2), word_); \
    } } while (0)

#define DRAIN_COUNT(CTRP) do { \
    asm volatile("s_waitcnt vmcnt(0)" ::: "memory"); \
    if ((ct & 63) == 0) \
        __hip_atomic_fetch_add((CTRP), 1u, __ATOMIC_RELAXED, __HIP_MEMORY_SCOPE_AGENT); \
    } while (0)

// ---------------- main: 8 groups x 32 row-slice WGs; direct-publish exchange ----
__global__ __launch_bounds__(512) void lstm_group_kernel(
    const float* __restrict__ audio, const float* __restrict__ s_rt,
    const uint4* __restrict__ WA0, const uint4* __restrict__ WA1, const uint4* __restrict__ WAH,
    const float* __restrict__ bih0, const float* __restrict__ bhh0,
    const float* __restrict__ bih1, const float* __restrict__ bhh1,
    const float* __restrict__ b1, u32* __restrict__ ctr,
    u64* __restrict__ gh1u, u64* __restrict__ gh2u,
    f16* __restrict__ ybuf, float* __restrict__ gsum, float* __restrict__ gsq)
{
    __shared__ __align__(16) f16 Xa[32][264];   // audio(t+1) staging       16,896 B
    __shared__ __align__(16) f16 Xh2[32][264];  // h2(t) staged (head)      16,896 B
    __shared__ float zz[8][32][36];             // per-wave partials        36,864 B
    __shared__ float bc0s[32], bc1s[32], b1s[4];
    __shared__ float pad_[2700];                // force 1 WG/CU (>80 KiB total)

    const int tid = threadIdx.x;
    const int w = blockIdx.x >> 3;     // row-slice 0..31
    const int g = blockIdx.x & 7;      // group 0..7
    const int wv = tid >> 6;
    const int lane = tid & 63;
    const int n32 = lane & 31;
    const int h32 = (lane >> 5) & 1;
    const int ct = tid - 256;          // cell threads = waves 4..7
    const int cb = ct >> 3, cj = ct & 7;
    const int ab0 = tid >> 6, aq0 = tid & 63;   // audio prefetch mapping

    if (tid == 0) { volatile float* vp = pad_; vp[0] = 0.f; }

    u32* const ctr1 = ctr + (g * 2 + 0) * 32;
    u32* const ctr2 = ctr + (g * 2 + 1) * 32;
    u64* const src1 = gh1u + (size_t)g * 2048;
    u64* const src2 = gh2u + (size_t)g * 2048;
    const size_t gbase = (size_t)n32 * 64 + 8 * wv + 2 * h32;

    // ---- persistent A-fragments ----
    uint4 a0[6], a1[4], ah[8] = {};
    #pragma unroll
    for (int ks = 0; ks < 6; ++ks) a0[ks] = WA0[((w * 8 + wv) * 6 + ks) * 64 + lane];
    #pragma unroll
    for (int ks = 0; ks < 4; ++ks) a1[ks] = WA1[((w * 8 + wv) * 4 + ks) * 64 + lane];
    if (wv < 2) {
        #pragma unroll
        for (int ks = 0; ks < 8; ++ks) ah[ks] = WAH[(w * 8 + ks) * 64 + lane];
    }

    if (tid < 32) {
        int r = ((tid >> 3) << 8) + 8 * w + (tid & 7);
        bc0s[tid] = bih0[r] + bhh0[r];
        bc1s[tid] = bih1[r] + bhh1[r];
    }
    if (tid < 4) b1s[tid] = b1[4 * w + tid];

    // ---- init: prev_out -> Xh2, audio(0) -> Xa ----
    for (int it = tid; it < 32 * 256; it += 512) {
        int b = it >> 8, c = it & 255;
        const float* sp = s_rt + ((size_t)(32 * g + b) * 16) * 256 + c;
        float s = 0.f;
        #pragma unroll
        for (int l = 0; l < 16; ++l) s += sp[l * 256];
        Xh2[b][c] = (f16)(s * 0.0625f);
        Xa[b][c] = (f16)audio[((size_t)(32 * g + b) * 512) * 256 + c];
    }
    // prologue audio prefetch: audio(1) into registers (held one step)
    float4 av0, av1, av2, av3;
    {
        const float4* a4 = (const float4*)audio;
        size_t base = 64 + aq0;
        av0 = a4[(size_t)(32 * g + ab0) * 32768 + base];
        av1 = a4[(size_t)(32 * g + ab0 + 8) * 32768 + base];
        av2 = a4[(size_t)(32 * g + ab0 + 16) * 32768 + base];
        av3 = a4[(size_t)(32 * g + ab0 + 24) * 32768 + base];
    }
    __syncthreads();

    u32x4 f20 = *(const u32x4*)&Xh2[n32][32 * wv + 8 * h32];
    u32x4 f21 = *(const u32x4*)&Xh2[n32][32 * wv + 16 + 8 * h32];
    u32x4 f10 = {0, 0, 0, 0}, f11 = {0, 0, 0, 0};
    f32x16 aAcc = {};
    MFMA32L(a0[2], &Xa[n32][32 * wv + 8 * h32], aAcc);
    MFMA32L(a0[3], &Xa[n32][32 * wv + 16 + 8 * h32], aAcc);

    float c1 = 0.f, c2 = 0.f;
    float ys0 = 0, ys1 = 0, ys2 = 0, ys3 = 0, yq0 = 0, yq1 = 0, yq2 = 0, yq3 = 0;

    for (int t = 0; t < TT; ++t) {
        const u32 T = (u32)(t + 1);
        // ---- A-finish: h2(t-1)/prev_out part ----
        MFMA32R(a0[0], f20, aAcc);
        MFMA32R(a0[1], f21, aAcc);
        ZZWR(wv, aAcc);
        __syncthreads();   // #1 (zz-A complete)

        // ---- window1: cell L0 publishes; all waves do Dacc h2-part; head(t-1) ----
        f32x16 Dacc = {};
        if (wv >= 4) {
            CELL_PUBLISH(bc0s, c1, src1, ctr1);
            if (t > 0) { MFMA32R(a1[2], f20, Dacc); MFMA32R(a1[3], f21, Dacc); }
            DRAIN_COUNT(ctr1);
        } else {
            if (t > 0) { MFMA32R(a1[2], f20, Dacc); MFMA32R(a1[3], f21, Dacc); }
            if (wv < 2 && t > 0) HEAD_BODY(t - 1);
        }
        // pack audio(t+1) from regs (issued last step) -> Xa
        if (t + 1 < TT) {
            #define AST(AV, S) do { \
                int b_ = ab0 + 8 * (S); \
                h2_t p0_; p0_.x = (f16)(AV).x; p0_.y = (f16)(AV).y; \
                h2_t p1_; p1_.x = (f16)(AV).z; p1_.y = (f16)(AV).w; \
                uint2 pv_; pv_.x = __builtin_bit_cast(u32, p0_); pv_.y = __builtin_bit_cast(u32, p1_); \
                *(uint2*)&Xa[b_][4 * aq0] = pv_; } while (0)
            AST(av0, 0); AST(av1, 1); AST(av2, 2); AST(av3, 3);
        }
        // per-wave poll, then gather h1(t) straight into B-fragments
        POLL(ctr1, 128u * T);
        GATHER2(f10, f11, (const void*)(src1 + gbase), (const void*)(src1 + gbase + 4));
        // issue audio(t+2) prefetch (consumed next step; fully hidden)
        if (t + 2 < TT) {
            const float4* a4 = (const float4*)audio;
            size_t base = (size_t)(t + 2) * 64 + aq0;
            av0 = a4[(size_t)(32 * g + ab0) * 32768 + base];
            av1 = a4[(size_t)(32 * g + ab0 + 8) * 32768 + base];
            av2 = a4[(size_t)(32 * g + ab0 + 16) * 32768 + base];
            av3 = a4[(size_t)(32 * g + ab0 + 24) * 32768 + base];
        }
        // ---- D: L1 h1-part ----
        MFMA32R(a1[0], f10, Dacc);
        MFMA32R(a1[1], f11, Dacc);
        ZZWR(wv, Dacc);
        __syncthreads();   // #2 (zz-D + Xa complete)

        // ---- window2: cell L1 publishes; all waves do A-pre for t+1 ----
        aAcc = (f32x16){};
        if (wv >= 4) {
            CELL_PUBLISH(bc1s, c2, src2, ctr2);
            if (t + 1 < TT) {
                MFMA32L(a0[2], &Xa[n32][32 * wv + 8 * h32], aAcc);
                MFMA32L(a0[3], &Xa[n32][32 * wv + 16 + 8 * h32], aAcc);
                MFMA32R(a0[4], f10, aAcc);
                MFMA32R(a0[5], f11, aAcc);
            }
            DRAIN_COUNT(ctr2);
        } else {
            if (t + 1 < TT) {
                MFMA32L(a0[2], &Xa[n32][32 * wv + 8 * h32], aAcc);
                MFMA32L(a0[3], &Xa[n32][32 * wv + 16 + 8 * h32], aAcc);
                MFMA32R(a0[4], f10, aAcc);
                MFMA32R(a0[5], f11, aAcc);
            }
        }
        // per-wave poll, gather h2(t), stage Xh2 for next step's head
        POLL(ctr2, 128u * T);
        GATHER2(f20, f21, (const void*)(src2 + gbase), (const void*)(src2 + gbase + 4));
        *(u32x4*)&Xh2[n32][32 * wv + 8 * h32] = f20;
        *(u32x4*)&Xh2[n32][32 * wv + 16 + 8 * h32] = f21;
        __syncthreads();   // #3 (Xh2 ready; zz reuse boundary)
    }
    // ---- epilogue: head for t = TT-1 ----
    if (wv < 2) HEAD_BODY(TT - 1);
    // ---- BN stats reduce (waves 0,1; lanes 0..15) ----
    if (wv < 2 && lane < 16) {
        #pragma unroll
        for (int m = 8; m >= 1; m >>= 1) {
            ys0 += __shfl_xor(ys0, m, 64); ys1 += __shfl_xor(ys1, m, 64);
            ys2 += __shfl_xor(ys2, m, 64); ys3 += __shfl_xor(ys3, m, 64);
            yq0 += __shfl_xor(yq0, m, 64); yq1 += __shfl_xor(yq1, m, 64);
            yq2 += __shfl_xor(yq2, m, 64); yq3 += __shfl_xor(yq3, m, 64);
        }
        if (lane == 0) {
            atomicAdd(&gsum[4 * w + 0], ys0); atomicAdd(&gsum[4 * w + 1], ys1);
            atomicAdd(&gsum[4 * w + 2], ys2); atomicAdd(&gsum[4 * w + 3], ys3);
            atomicAdd(&gsq[4 * w + 0], yq0); atomicAdd(&gsq[4 * w + 1], yq1);
            atomicAdd(&gsq[4 * w + 2], yq2); atomicAdd(&gsq[4 * w + 3], yq3);
        }
    }
}

// ---------------- final head: BN(train) + ReLU + Linear(128->6) ----------------
__global__ __launch_bounds__(256) void head_kernel(
    const f16* __restrict__ ybuf, const float* __restrict__ gsum, const float* __restrict__ gsq,
    const float* __restrict__ gamma, const float* __restrict__ beta,
    const float* __restrict__ W2, const float* __restrict__ b2,
    float* __restrict__ out)
{
    __shared__ float sc[NF], sh[NF], W2s[6 * NF], b2s[6];
    const int tid = threadIdx.x;
    if (tid < NF) {
        const float invN = 1.f / (float)NTOT;
        float mu = gsum[tid] * invN;
        float var = gsq[tid] * invN - mu * mu;
        float iv = rsqrtf(var + 1e-5f);
        float s = gamma[tid] * iv;
        sc[tid] = s;
        sh[tid] = beta[tid] - mu * s;
    }
    for (int i = tid; i < 6 * NF; i += 256) W2s[i] = W2[i];
    if (tid < 6) b2s[tid] = b2[tid];
    __syncthreads();

    size_t n = (size_t)blockIdx.x * 256 + tid;
    const h2_t* yr = (const h2_t*)(ybuf + n * NF);
    float a0 = b2s[0], a1 = b2s[1], a2 = b2s[2], a3 = b2s[3], a4 = b2s[4], a5 = b2s[5];
    #pragma unroll 8
    for (int p = 0; p < 64; ++p) {
        h2_t v = yr[p];
        int f0 = 2 * p, f1 = 2 * p + 1;
        float v0 = fmaxf(fmaf((float)v.x, sc[f0], sh[f0]), 0.f);
        float v1 = fmaxf(fmaf((float)v.y, sc[f1], sh[f1]), 0.f);
        a0 = fmaf(v0, W2s[0 * NF + f0], a0); a0 = fmaf(v1, W2s[0 * NF + f1], a0);
        a1 = fmaf(v0, W2s[1 * NF + f0], a1); a1 = fmaf(v1, W2s[1 * NF + f1], a1);
        a2 = fmaf(v0, W2s[2 * NF + f0], a2); a2 = fmaf(v1, W2s[2 * NF + f1], a2);
        a3 = fmaf(v0, W2s[3 * NF + f0], a3); a3 = fmaf(v1, W2s[3 * NF + f1], a3);
        a4 = fmaf(v0, W2s[4 * NF + f0], a4); a4 = fmaf(v1, W2s[4 * NF + f1], a4);
        a5 = fmaf(v0, W2s[5 * NF + f0], a5); a5 = fmaf(v1, W2s[5 * NF + f1], a5);
    }
    float* op = out + n * 6;
    op[0] = a0; op[1] = a1; op[2] = a2; op[3] = a3; op[4] = a4; op[5] = a5;
}

extern "C" void kernel_launch(void* const* d_in, const int* in_sizes, int n_in,
                              void* d_out, int out_size, void* d_ws, size_t ws_size,
                              hipStream_t stream) {
    const float* audio = (const float*)d_in[1];
    const float* s_rt  = (const float*)d_in[2];
    const float* Wih0  = (const float*)d_in[3];
    const float* Whh0  = (const float*)d_in[4];
    const float* bih0  = (const float*)d_in[5];
    const float* bhh0  = (const float*)d_in[6];
    const float* Wih1  = (const float*)d_in[7];
    const float* Whh1  = (const float*)d_in[8];
    const float* bih1  = (const float*)d_in[9];
    const float* bhh1  = (const float*)d_in[10];
    const float* W1    = (const float*)d_in[11];
    const float* b1    = (const float*)d_in[12];
    const float* gamma = (const float*)d_in[13];
    const float* beta  = (const float*)d_in[14];
    const float* W2    = (const float*)d_in[15];
    const float* b2    = (const float*)d_in[16];

    char* ws = (char*)d_ws;
    f16* WA0    = (f16*)(ws + OFF_WA0);
    f16* WA1    = (f16*)(ws + OFF_WA1);
    f16* WAH    = (f16*)(ws + OFF_WAH);
    float* gsum = (float*)(ws + OFF_GSUM);
    float* gsq  = (float*)(ws + OFF_GSQ);
    u32* ctrp   = (u32*)(ws + OFF_CTR);
    u64* gh1u   = (u64*)(ws + OFF_GH1);
    u64* gh2u   = (u64*)(ws + OFF_GH2);
    f16* ybuf   = (f16*)(ws + OFF_Y);
    float* out  = (float*)d_out;

    // prep: 786432 + 524288 + 131072 + 256 + 512 = 1,442,560 = 5635 * 256
    prep_kernel<<<5635, 256, 0, stream>>>(Wih0, Whh0, Wih1, Whh1, W1,
                                          WA0, WA1, WAH, gsum, ctrp);

    lstm_group_kernel<<<256, 512, 0, stream>>>(audio, s_rt,
                                               (const uint4*)WA0, (const uint4*)WA1, (const uint4*)WAH,
                                               bih0, bhh0, bih1, bhh1, b1, ctrp,
                                               gh1u, gh2u, ybuf, gsum, gsq);

    head_kernel<<<NTOT / 256, 256, 0, stream>>>(ybuf, gsum, gsq, gamma, beta, W2, b2, out);
}

// Round 10
// 2968.662 us; speedup vs baseline: 4.4603x; 4.4603x over previous
//
#include <hip/hip_runtime.h>
#include <stdint.h>

typedef unsigned int u32;
typedef unsigned short u16;
typedef unsigned long long u64;
typedef _Float16 f16;
typedef _Float16 h2_t __attribute__((ext_vector_type(2)));
typedef _Float16 f16x4 __attribute__((ext_vector_type(4)));
typedef _Float16 f16x8 __attribute__((ext_vector_type(8)));
typedef float f32x4 __attribute__((ext_vector_type(4)));
typedef float f32x16 __attribute__((ext_vector_type(16)));
typedef u32 u32x4 __attribute__((ext_vector_type(4)));

#define TT 512
#define NF 128
#define NTOT (256 * TT)

// ---- ws layout (bytes) ----
#define OFF_WA0   0u          // 786432 f16 = 1,572,864
#define OFF_WA1   1572864u    // 524288 f16 = 1,048,576
#define OFF_WAH   2621440u    // 131072 f16 =   262,144
#define OFF_GSUM  2883584u    // 128 f32 (+pad)
#define OFF_GSQ   2884096u    // 128 f32 (+pad)
#define OFF_CTR   2884608u    // 512 u32 (16 counters, 128B apart)
#define OFF_GH1   2886656u    // 8 groups * 2048 u64 = 131,072
#define OFF_GH2   3017728u    // 131,072
#define OFF_Y     3148800u    // 131072*128 f16 = 33,554,432

__device__ __forceinline__ float sigf(float x) { return 1.0f / (1.0f + __expf(-x)); }
__device__ __forceinline__ float tanh_fast(float x) { return 1.0f - 2.0f / (__expf(2.0f * x) + 1.0f); }

// ---------------- prep: pack weights into per-wave MFMA A-fragments (same as r8) --------
__global__ void prep_kernel(const float* __restrict__ Wih0, const float* __restrict__ Whh0,
                            const float* __restrict__ Wih1, const float* __restrict__ Whh1,
                            const float* __restrict__ W1,
                            f16* __restrict__ WA0, f16* __restrict__ WA1, f16* __restrict__ WAH,
                            float* __restrict__ gz, u32* __restrict__ ctr) {
    int idx = blockIdx.x * 256 + threadIdx.x;
    const int n0 = 786432, n1 = 524288, n2 = 131072;
    if (idx < n0) {
        int u = idx >> 9, r9 = idx & 511;
        int lane = r9 >> 3, j = r9 & 7;
        int ks = u % 6; u /= 6;
        int wv = u & 7, w = u >> 3;
        int lr = lane & 31, h = lane >> 5;
        int r = ((lr >> 3) << 8) + 8 * w + (lr & 7);
        int seg = ks >> 1, sig = ks & 1;
        int c = 256 * seg + 32 * wv + 16 * sig + 8 * h + j;
        float v = (c < 512) ? Wih0[r * 512 + c] : Whh0[r * 256 + (c - 512)];
        WA0[idx] = (f16)v;
    } else if (idx < n0 + n1) {
        int i2 = idx - n0;
        int lane = (i2 >> 3) & 63, j = i2 & 7;
        int ks = (i2 >> 9) & 3, wv = (i2 >> 11) & 7, w = i2 >> 14;
        int lr = lane & 31, h = lane >> 5;
        int r = ((lr >> 3) << 8) + 8 * w + (lr & 7);
        int sig = ks & 1;
        int c = 32 * wv + 16 * sig + 8 * h + j;
        float v = (ks >> 1) ? Whh1[r * 256 + c] : Wih1[r * 256 + c];
        WA1[i2] = (f16)v;
    } else if (idx < n0 + n1 + n2) {
        int i2 = idx - n0 - n1;
        int u = i2 >> 9, r9 = i2 & 511;
        int lane = r9 >> 3, j = r9 & 7;
        int ks = u & 7, w = u >> 3;
        int m = lane & 15, hh = lane >> 4;
        int k = 32 * ks + 8 * hh + j;
        float v = (m < 4) ? W1[(4 * w + m) * 256 + k] : 0.f;
        WAH[i2] = (f16)v;
    } else if (idx < n0 + n1 + n2 + 256) {
        gz[idx - n0 - n1 - n2] = 0.f;     // gsum[128] + gsq[128]
    } else if (idx < n0 + n1 + n2 + 256 + 512) {
        ctr[idx - n0 - n1 - n2 - 256] = 0u;
    }
}

#define MFMA32L(A, BP, C) (C) = __builtin_amdgcn_mfma_f32_32x32x16_f16( \
    __builtin_bit_cast(f16x8, (A)), __builtin_bit_cast(f16x8, *(const uint4*)(BP)), (C), 0, 0, 0)
#define MFMA32R(A, B, C) (C) = __builtin_amdgcn_mfma_f32_32x32x16_f16( \
    __builtin_bit_cast(f16x8, (A)), __builtin_bit_cast(f16x8, (B)), (C), 0, 0, 0)

#define ZZWR(KW, C) do { \
    f32x4 v0_ = {(C)[0], (C)[1], (C)[2], (C)[3]};    *(f32x4*)&zz[KW][n32][4 * h32] = v0_; \
    f32x4 v1_ = {(C)[4], (C)[5], (C)[6], (C)[7]};    *(f32x4*)&zz[KW][n32][8 + 4 * h32] = v1_; \
    f32x4 v2_ = {(C)[8], (C)[9], (C)[10], (C)[11]};  *(f32x4*)&zz[KW][n32][16 + 4 * h32] = v2_; \
    f32x4 v3_ = {(C)[12], (C)[13], (C)[14], (C)[15]}; *(f32x4*)&zz[KW][n32][24 + 4 * h32] = v3_; } while (0)

// coherent (device-visible) wide exchange primitives
#define GATHER2(F0, F1, P0, P1) asm volatile( \
    "global_load_dwordx4 %0, %2, off sc0 sc1\n\t" \
    "global_load_dwordx4 %1, %3, off sc0 sc1\n\t" \
    "s_waitcnt vmcnt(0)" \
    : "=&v"(F0), "=&v"(F1) : "v"(P0), "v"(P1) : "memory")

#define PUBX4(PTR, DATA) asm volatile( \
    "global_store_dwordx4 %0, %1, off sc0 sc1" :: "v"(PTR), "v"(DATA) : "memory")

#define HEAD_BODY(TIDX) do { \
    f32x4 C_ = {}; \
    _Pragma("unroll") \
    for (int ks_ = 0; ks_ < 8; ++ks_) \
        C_ = __builtin_amdgcn_mfma_f32_16x16x32_f16( \
            __builtin_bit_cast(f16x8, ah[ks_]), \
            __builtin_bit_cast(f16x8, \
                *(const uint4*)&Xh2[wv * 16 + (lane & 15)][32 * ks_ + 8 * ((lane >> 4) & 3)]), \
            C_, 0, 0, 0); \
    if (lane < 16) { \
        float y0 = C_[0] + b1s[0], y1 = C_[1] + b1s[1]; \
        float y2 = C_[2] + b1s[2], y3 = C_[3] + b1s[3]; \
        ys0 += y0; yq0 += y0 * y0; ys1 += y1; yq1 += y1 * y1; \
        ys2 += y2; yq2 += y2 * y2; ys3 += y3; yq3 += y3 * y3; \
        f16x4 yp; yp[0] = (f16)y0; yp[1] = (f16)y1; yp[2] = (f16)y2; yp[3] = (f16)y3; \
        int b_ = wv * 16 + lane; \
        ((u64*)ybuf)[((size_t)(g * 32 + b_) * 512 + (TIDX)) * 32 + w] = __builtin_bit_cast(u64, yp); \
    } } while (0)

// cell math + shfl-collapse + direct 16B publish (layout verified in r9: passed)
#define CELL_PUB(BCS, CSTATE, SRC) do { \
    float z0 = BCS[cj], z1 = BCS[8 + cj], z2 = BCS[16 + cj], z3 = BCS[24 + cj]; \
    _Pragma("unroll") \
    for (int kw_ = 0; kw_ < 8; ++kw_) { \
        z0 += zz[kw_][cb][cj];      z1 += zz[kw_][cb][8 + cj]; \
        z2 += zz[kw_][cb][16 + cj]; z3 += zz[kw_][cb][24 + cj]; \
    } \
    float c_ = sigf(z1) * (CSTATE) + sigf(z0) * tanh_fast(z2); \
    (CSTATE) = c_; \
    f16 hf_ = (f16)(sigf(z3) * tanh_fast(c_)); \
    u32 hb_ = (u32)__builtin_bit_cast(u16, hf_); \
    u32 p01_ = hb_ | ((u32)__shfl_xor((int)hb_, 1, 64) << 16); \
    u32 p23_ = (u32)__shfl_xor((int)p01_, 2, 64); \
    u32 p45_ = (u32)__shfl_xor((int)p01_, 4, 64); \
    u32 p67_ = (u32)__shfl_xor((int)p23_, 4, 64); \
    if (cj == 0) { \
        u32x4 word_ = {p01_, p23_, p45_, p67_}; \
        PUBX4((void*)((SRC) + ((cb << 5) + w) * 2), word_); \
    } } while (0)

// drain own stores, LDS-funnel to wave7, single global add + single poller, barrier releases
#define FUNNEL_SYNC(LF, CTRP, T) do { \
    asm volatile("s_waitcnt vmcnt(0)" ::: "memory"); \
    if (lane == 0) \
        __hip_atomic_fetch_add(&(LF), 1u, __ATOMIC_RELAXED, __HIP_MEMORY_SCOPE_WORKGROUP); \
    if (wv == 7 && lane == 0) { \
        int gu_ = 0; \
        while (__hip_atomic_load(&(LF), __ATOMIC_RELAXED, __HIP_MEMORY_SCOPE_WORKGROUP) < 4u * (T) \
               && ++gu_ < 100000000) {} \
        __hip_atomic_fetch_add((CTRP), 1u, __ATOMIC_RELAXED, __HIP_MEMORY_SCOPE_AGENT); \
        gu_ = 0; \
        while (__hip_atomic_load((CTRP), __ATOMIC_RELAXED, __HIP_MEMORY_SCOPE_AGENT) < 32u * (T) \
               && ++gu_ < 100000000) {} \
    } } while (0)

// ---------------- main: 8 groups x 32 row-slice WGs; funneled direct-publish exchange ----
__global__ __launch_bounds__(512) void lstm_group_kernel(
    const float* __restrict__ audio, const float* __restrict__ s_rt,
    const uint4* __restrict__ WA0, const uint4* __restrict__ WA1, const uint4* __restrict__ WAH,
    const float* __restrict__ bih0, const float* __restrict__ bhh0,
    const float* __restrict__ bih1, const float* __restrict__ bhh1,
    const float* __restrict__ b1, u32* __restrict__ ctr,
    u64* __restrict__ gh1u, u64* __restrict__ gh2u,
    f16* __restrict__ ybuf, float* __restrict__ gsum, float* __restrict__ gsq)
{
    __shared__ __align__(16) f16 Xa[32][264];   // audio(t+1) staging       16,896 B
    __shared__ __align__(16) f16 Xh2[32][264];  // h2(t) staged (head)      16,896 B
    __shared__ float zz[8][32][36];             // per-wave partials        36,864 B
    __shared__ float bc0s[32], bc1s[32], b1s[4];
    __shared__ u32 lflag[2];                    // per-window LDS funnel counters
    __shared__ float pad_[2700];                // force 1 WG/CU (>80 KiB total)

    const int tid = threadIdx.x;
    const int w = blockIdx.x >> 3;     // row-slice 0..31
    const int g = blockIdx.x & 7;      // group 0..7
    const int wv = tid >> 6;
    const int lane = tid & 63;
    const int n32 = lane & 31;
    const int h32 = (lane >> 5) & 1;
    const int ct = tid - 256;          // cell threads = waves 4..7
    const int cb = ct >> 3, cj = ct & 7;
    const int bg = tid >> 6, aq = tid & 63;    // audio mapping (waves 0..3)

    if (tid == 0) { volatile float* vp = pad_; vp[0] = 0.f; lflag[0] = 0u; lflag[1] = 0u; }

    u32* const ctr1 = ctr + (g * 2 + 0) * 32;
    u32* const ctr2 = ctr + (g * 2 + 1) * 32;
    u64* const src1 = gh1u + (size_t)g * 2048;
    u64* const src2 = gh2u + (size_t)g * 2048;
    const size_t gbase = (size_t)n32 * 64 + 8 * wv + 2 * h32;
    const float4* const a4 = (const float4*)audio;

    // ---- persistent A-fragments ----
    uint4 a0[6], a1[4], ah[8] = {};
    #pragma unroll
    for (int ks = 0; ks < 6; ++ks) a0[ks] = WA0[((w * 8 + wv) * 6 + ks) * 64 + lane];
    #pragma unroll
    for (int ks = 0; ks < 4; ++ks) a1[ks] = WA1[((w * 8 + wv) * 4 + ks) * 64 + lane];
    if (wv < 2) {
        #pragma unroll
        for (int ks = 0; ks < 8; ++ks) ah[ks] = WAH[(w * 8 + ks) * 64 + lane];
    }

    if (tid < 32) {
        int r = ((tid >> 3) << 8) + 8 * w + (tid & 7);
        bc0s[tid] = bih0[r] + bhh0[r];
        bc1s[tid] = bih1[r] + bhh1[r];
    }
    if (tid < 4) b1s[tid] = b1[4 * w + tid];

    // ---- init: prev_out -> Xh2, audio(0) -> Xa ----
    for (int it = tid; it < 32 * 256; it += 512) {
        int b = it >> 8, c = it & 255;
        const float* sp = s_rt + ((size_t)(32 * g + b) * 16) * 256 + c;
        float s = 0.f;
        #pragma unroll
        for (int l = 0; l < 16; ++l) s += sp[l * 256];
        Xh2[b][c] = (f16)(s * 0.0625f);
        Xa[b][c] = (f16)audio[((size_t)(32 * g + b) * 512) * 256 + c];
    }
    // prologue: audio(1) into registers (waves 0..3, 8 batches each)
    float4 av[8];
    if (wv < 4) {
        #pragma unroll
        for (int s = 0; s < 8; ++s)
            av[s] = a4[(size_t)(32 * g + 8 * bg + s) * 32768 + 64 + aq];
    }
    __syncthreads();

    u32x4 f20 = *(const u32x4*)&Xh2[n32][32 * wv + 8 * h32];
    u32x4 f21 = *(const u32x4*)&Xh2[n32][32 * wv + 16 + 8 * h32];
    u32x4 f10 = {0, 0, 0, 0}, f11 = {0, 0, 0, 0};
    f32x16 aAcc = {};
    MFMA32L(a0[2], &Xa[n32][32 * wv + 8 * h32], aAcc);
    MFMA32L(a0[3], &Xa[n32][32 * wv + 16 + 8 * h32], aAcc);

    float c1 = 0.f, c2 = 0.f;
    float ys0 = 0, ys1 = 0, ys2 = 0, ys3 = 0, yq0 = 0, yq1 = 0, yq2 = 0, yq3 = 0;

    for (int t = 0; t < TT; ++t) {
        const u32 T = (u32)(t + 1);
        // ---- A-finish: h2(t-1)/prev_out part ----
        MFMA32R(a0[0], f20, aAcc);
        MFMA32R(a0[1], f21, aAcc);
        ZZWR(wv, aAcc);
        __syncthreads();   // #1 (zz-A complete)

        // ---- window1: cells publish h1; others Dacc h2-part + head(t-1) + pack audio ----
        f32x16 Dacc = {};
        if (wv >= 4) {
            CELL_PUB(bc0s, c1, src1);
            if (t > 0) { MFMA32R(a1[2], f20, Dacc); MFMA32R(a1[3], f21, Dacc); }
            FUNNEL_SYNC(lflag[0], ctr1, T);
        } else {
            if (t > 0) { MFMA32R(a1[2], f20, Dacc); MFMA32R(a1[3], f21, Dacc); }
            if (wv < 2 && t > 0) HEAD_BODY(t - 1);
            if (t + 1 < TT) {
                #pragma unroll
                for (int s = 0; s < 8; ++s) {
                    h2_t p0_; p0_.x = (f16)av[s].x; p0_.y = (f16)av[s].y;
                    h2_t p1_; p1_.x = (f16)av[s].z; p1_.y = (f16)av[s].w;
                    uint2 pv_;
                    pv_.x = __builtin_bit_cast(u32, p0_);
                    pv_.y = __builtin_bit_cast(u32, p1_);
                    *(uint2*)&Xa[8 * bg + s][4 * aq] = pv_;
                }
            }
        }
        __syncthreads();   // #2 (release; Xa(t+1) ready)

        // ---- gather h1(t) -> B-fragments; issue audio(t+2) (waves 0..3) ----
        GATHER2(f10, f11, (const void*)(src1 + gbase), (const void*)(src1 + gbase + 4));
        if (wv < 4 && t + 2 < TT) {
            #pragma unroll
            for (int s = 0; s < 8; ++s)
                av[s] = a4[(size_t)(32 * g + 8 * bg + s) * 32768 + (size_t)(t + 2) * 64 + aq];
        }
        // ---- D: L1 h1-part ----
        MFMA32R(a1[0], f10, Dacc);
        MFMA32R(a1[1], f11, Dacc);
        ZZWR(wv, Dacc);
        __syncthreads();   // #3 (zz-D complete)

        // ---- window2: cells publish h2; all waves A-pre for t+1 ----
        aAcc = (f32x16){};
        if (wv >= 4) {
            CELL_PUB(bc1s, c2, src2);
            if (t + 1 < TT) {
                MFMA32L(a0[2], &Xa[n32][32 * wv + 8 * h32], aAcc);
                MFMA32L(a0[3], &Xa[n32][32 * wv + 16 + 8 * h32], aAcc);
                MFMA32R(a0[4], f10, aAcc);
                MFMA32R(a0[5], f11, aAcc);
            }
            FUNNEL_SYNC(lflag[1], ctr2, T);
        } else {
            if (t + 1 < TT) {
                MFMA32L(a0[2], &Xa[n32][32 * wv + 8 * h32], aAcc);
                MFMA32L(a0[3], &Xa[n32][32 * wv + 16 + 8 * h32], aAcc);
                MFMA32R(a0[4], f10, aAcc);
                MFMA32R(a0[5], f11, aAcc);
            }
        }
        __syncthreads();   // #4 (release)

        // ---- gather h2(t) -> fragments + stage Xh2 for next step's head ----
        GATHER2(f20, f21, (const void*)(src2 + gbase), (const void*)(src2 + gbase + 4));
        *(u32x4*)&Xh2[n32][32 * wv + 8 * h32] = f20;
        *(u32x4*)&Xh2[n32][32 * wv + 16 + 8 * h32] = f21;
        // no barrier: Xh2 readers (head) separated by sync #1/#2 of t+1
    }
    // ---- epilogue: head for t = TT-1 ----
    __syncthreads();
    if (wv < 2) HEAD_BODY(TT - 1);
    // ---- BN stats reduce (waves 0,1; lanes 0..15) ----
    if (wv < 2 && lane < 16) {
        #pragma unroll
        for (int m = 8; m >= 1; m >>= 1) {
            ys0 += __shfl_xor(ys0, m, 64); ys1 += __shfl_xor(ys1, m, 64);
            ys2 += __shfl_xor(ys2, m, 64); ys3 += __shfl_xor(ys3, m, 64);
            yq0 += __shfl_xor(yq0, m, 64); yq1 += __shfl_xor(yq1, m, 64);
            yq2 += __shfl_xor(yq2, m, 64); yq3 += __shfl_xor(yq3, m, 64);
        }
        if (lane == 0) {
            atomicAdd(&gsum[4 * w + 0], ys0); atomicAdd(&gsum[4 * w + 1], ys1);
            atomicAdd(&gsum[4 * w + 2], ys2); atomicAdd(&gsum[4 * w + 3], ys3);
            atomicAdd(&gsq[4 * w + 0], yq0); atomicAdd(&gsq[4 * w + 1], yq1);
            atomicAdd(&gsq[4 * w + 2], yq2); atomicAdd(&gsq[4 * w + 3], yq3);
        }
    }
}

// ---------------- final head: BN(train) + ReLU + Linear(128->6) ----------------
__global__ __launch_bounds__(256) void head_kernel(
    const f16* __restrict__ ybuf, const float* __restrict__ gsum, const float* __restrict__ gsq,
    const float* __restrict__ gamma, const float* __restrict__ beta,
    const float* __restrict__ W2, const float* __restrict__ b2,
    float* __restrict__ out)
{
    __shared__ float sc[NF], sh[NF], W2s[6 * NF], b2s[6];
    const int tid = threadIdx.x;
    if (tid < NF) {
        const float invN = 1.f / (float)NTOT;
        float mu = gsum[tid] * invN;
        float var = gsq[tid] * invN - mu * mu;
        float iv = rsqrtf(var + 1e-5f);
        float s = gamma[tid] * iv;
        sc[tid] = s;
        sh[tid] = beta[tid] - mu * s;
    }
    for (int i = tid; i < 6 * NF; i += 256) W2s[i] = W2[i];
    if (tid < 6) b2s[tid] = b2[tid];
    __syncthreads();

    size_t n = (size_t)blockIdx.x * 256 + tid;
    const h2_t* yr = (const h2_t*)(ybuf + n * NF);
    float a0 = b2s[0], a1 = b2s[1], a2 = b2s[2], a3 = b2s[3], a4 = b2s[4], a5 = b2s[5];
    #pragma unroll 8
    for (int p = 0; p < 64; ++p) {
        h2_t v = yr[p];
        int f0 = 2 * p, f1 = 2 * p + 1;
        float v0 = fmaxf(fmaf((float)v.x, sc[f0], sh[f0]), 0.f);
        float v1 = fmaxf(fmaf((float)v.y, sc[f1], sh[f1]), 0.f);
        a0 = fmaf(v0, W2s[0 * NF + f0], a0); a0 = fmaf(v1, W2s[0 * NF + f1], a0);
        a1 = fmaf(v0, W2s[1 * NF + f0], a1); a1 = fmaf(v1, W2s[1 * NF + f1], a1);
        a2 = fmaf(v0, W2s[2 * NF + f0], a2); a2 = fmaf(v1, W2s[2 * NF + f1], a2);
        a3 = fmaf(v0, W2s[3 * NF + f0], a3); a3 = fmaf(v1, W2s[3 * NF + f1], a3);
        a4 = fmaf(v0, W2s[4 * NF + f0], a4); a4 = fmaf(v1, W2s[4 * NF + f1], a4);
        a5 = fmaf(v0, W2s[5 * NF + f0], a5); a5 = fmaf(v1, W2s[5 * NF + f1], a5);
    }
    float* op = out + n * 6;
    op[0] = a0; op[1] = a1; op[2] = a2; op[3] = a3; op[4] = a4; op[5] = a5;
}

extern "C" void kernel_launch(void* const* d_in, const int* in_sizes, int n_in,
                              void* d_out, int out_size, void* d_ws, size_t ws_size,
                              hipStream_t stream) {
    const float* audio = (const float*)d_in[1];
    const float* s_rt  = (const float*)d_in[2];
    const float* Wih0  = (const float*)d_in[3];
    const float* Whh0  = (const float*)d_in[4];
    const float* bih0  = (const float*)d_in[5];
    const float* bhh0  = (const float*)d_in[6];
    const float* Wih1  = (const float*)d_in[7];
    const float* Whh1  = (const float*)d_in[8];
    const float* bih1  = (const float*)d_in[9];
    const float* bhh1  = (const float*)d_in[10];
    const float* W1    = (const float*)d_in[11];
    const float* b1    = (const float*)d_in[12];
    const float* gamma = (const float*)d_in[13];
    const float* beta  = (const float*)d_in[14];
    const float* W2    = (const float*)d_in[15];
    const float* b2    = (const float*)d_in[16];

    char* ws = (char*)d_ws;
    f16* WA0    = (f16*)(ws + OFF_WA0);
    f16* WA1    = (f16*)(ws + OFF_WA1);
    f16* WAH    = (f16*)(ws + OFF_WAH);
    float* gsum = (float*)(ws + OFF_GSUM);
    float* gsq  = (float*)(ws + OFF_GSQ);
    u32* ctrp   = (u32*)(ws + OFF_CTR);
    u64* gh1u   = (u64*)(ws + OFF_GH1);
    u64* gh2u   = (u64*)(ws + OFF_GH2);
    f16* ybuf   = (f16*)(ws + OFF_Y);
    float* out  = (float*)d_out;

    // prep: 786432 + 524288 + 131072 + 256 + 512 = 1,442,560 = 5635 * 256
    prep_kernel<<<5635, 256, 0, stream>>>(Wih0, Whh0, Wih1, Whh1, W1,
                                          WA0, WA1, WAH, gsum, ctrp);

    lstm_group_kernel<<<256, 512, 0, stream>>>(audio, s_rt,
                                               (const uint4*)WA0, (const uint4*)WA1, (const uint4*)WAH,
                                               bih0, bhh0, bih1, bhh1, b1, ctrp,
                                               gh1u, gh2u, ybuf, gsum, gsq);

    head_kernel<<<NTOT / 256, 256, 0, stream>>>(ybuf, gsum, gsq, gamma, beta, W2, b2, out);
}